// Round 1
// baseline (560.011 us; speedup 1.0000x reference)
//
#include <hip/hip_runtime.h>

#define KCL 41
#define BB 8
#define CC 128
#define HWSZ 25600
#define PP 200          // chunks per (b,c) plane = HW/C
#define ASTRIDE 132     // padded row stride (floats) for A arrays / Stile

// ---------------- init: zero accumulators in workspace ----------------
__global__ __launch_bounds__(256) void init_ws(float* ws) {
    // G[41*41] + NS[41] + NT[41] + CNT[41] = 1804 dwords; zero bits valid for both f32 and i32
    for (int i = threadIdx.x; i < KCL * KCL + 3 * KCL; i += 256) ws[i] = 0.f;
}

// ---------------- main: per-(b,p) scatter + Gram partials ----------------
__global__ __launch_bounds__(256) void main_k(const float* __restrict__ fs,
                                              const float* __restrict__ ft,
                                              const int* __restrict__ labels,
                                              float* __restrict__ G,
                                              float* __restrict__ NS,
                                              float* __restrict__ NT,
                                              int* __restrict__ CNT)
{
    __shared__ int lab[128];
    __shared__ unsigned long long mask0[KCL], mask1[KCL];
    __shared__ float Stile[32 * ASTRIDE];   // 16.9 KB, one c-quarter of the 128x128 tile
    __shared__ float As[KCL * ASTRIDE];     // 21.6 KB
    __shared__ float At[KCL * ASTRIDE];     // 21.6 KB

    const int bp = blockIdx.x;
    const int b = bp / PP, p = bp % PP;
    const int tid = threadIdx.x;

    if (tid < 128) lab[tid] = labels[b * HWSZ + p * 128 + tid];
    __syncthreads();

    // per-class 64-bit ballot masks over the 128 shared labels
    const int wv = tid >> 6, ln = tid & 63;
    if (wv < 2) {
        int myl = lab[(wv << 6) + ln];
        for (int cl = 0; cl < KCL; ++cl) {
            unsigned long long mm = __ballot(myl == cl);
            if (ln == 0) (wv ? mask1 : mask0)[cl] = mm;
        }
    }
    __syncthreads();
    if (tid < KCL)
        atomicAdd(&CNT[tid], (int)(__popcll(mask0[tid]) + __popcll(mask1[tid])));

    const size_t base = (size_t)b * CC * HWSZ + (size_t)p * 128;

    // Build A[cl][c] = sum over j with label cl of feat[c][j], for both tensors.
    for (int tn = 0; tn < 2; ++tn) {
        const float* __restrict__ f = tn ? ft : fs;
        float* __restrict__ A = tn ? At : As;
        for (int q = 0; q < 4; ++q) {
            __syncthreads();   // previous scatter done reading Stile
            // stage rows c in [32q, 32q+32): 1024 float4 chunks, coalesced
            #pragma unroll
            for (int k = 0; k < 4; ++k) {
                int chunk = tid + (k << 8);
                int row = chunk >> 5;           // 0..31
                int j4  = (chunk & 31) << 2;    // 0..124
                int c   = (q << 5) + row;
                float4 v = *(const float4*)(f + base + (size_t)c * HWSZ + j4);
                *(float4*)(&Stile[row * ASTRIDE + j4]) = v;
            }
            __syncthreads();
            // 32 lanes scatter via uniform mask iteration -> register sums (no LDS RMW chains)
            if (tid < 32) {
                const int c = (q << 5) + tid;
                const float* srow = &Stile[tid * ASTRIDE];
                for (int cl = 0; cl < KCL; ++cl) {
                    float sum = 0.f;
                    unsigned long long mm = mask0[cl];
                    while (mm) { int j = __builtin_ctzll(mm); mm &= mm - 1; sum += srow[j]; }
                    mm = mask1[cl];
                    while (mm) { int j = __builtin_ctzll(mm); mm &= mm - 1; sum += srow[64 + j]; }
                    A[cl * ASTRIDE + c] = sum;
                }
            }
        }
    }
    __syncthreads();

    // Gram: G[i][j] += sum_c As[i][c] * At[j][c]; 16x16 threads x 3x3 register tile (48x48 >= 41x41)
    {
        const int ti = tid >> 4, tj = tid & 15;
        float acc[3][3] = {};
        for (int c4 = 0; c4 < 32; ++c4) {
            float4 av[3], bv[3];
            #pragma unroll
            for (int u = 0; u < 3; ++u) {
                int I = ti + (u << 4); if (I > KCL - 1) I = KCL - 1;  // clamped duplicate, discarded at write
                int J = tj + (u << 4); if (J > KCL - 1) J = KCL - 1;
                av[u] = *(const float4*)(&As[I * ASTRIDE + (c4 << 2)]);
                bv[u] = *(const float4*)(&At[J * ASTRIDE + (c4 << 2)]);
            }
            #pragma unroll
            for (int u = 0; u < 3; ++u)
                #pragma unroll
                for (int v = 0; v < 3; ++v)
                    acc[u][v] += av[u].x * bv[v].x + av[u].y * bv[v].y
                               + av[u].z * bv[v].z + av[u].w * bv[v].w;
        }
        #pragma unroll
        for (int u = 0; u < 3; ++u) {
            int I = ti + (u << 4); if (I >= KCL) continue;
            #pragma unroll
            for (int v = 0; v < 3; ++v) {
                int J = tj + (v << 4); if (J >= KCL) continue;
                atomicAdd(&G[I * KCL + J], acc[u][v]);
            }
        }
    }

    // squared-norm partials
    if (tid < KCL) {
        float ss = 0.f, tt = 0.f;
        for (int c4 = 0; c4 < 32; ++c4) {
            float4 a  = *(const float4*)(&As[tid * ASTRIDE + (c4 << 2)]);
            float4 b2 = *(const float4*)(&At[tid * ASTRIDE + (c4 << 2)]);
            ss += a.x * a.x + a.y * a.y + a.z * a.z + a.w * a.w;
            tt += b2.x * b2.x + b2.y * b2.y + b2.z * b2.z + b2.w * b2.w;
        }
        atomicAdd(&NS[tid], ss);
        atomicAdd(&NT[tid], tt);
    }
}

// ---------------- finalize: cosine logits, logsumexp, loss ----------------
__global__ void finalize(const float* __restrict__ G,
                         const float* __restrict__ NS,
                         const float* __restrict__ NT,
                         const int* __restrict__ CNT,
                         float* __restrict__ out)
{
    __shared__ float sn[KCL], tnn[KCL];
    const int t = threadIdx.x;  // 64 threads = 1 wave
    if (t < KCL) {
        sn[t]  = fmaxf(sqrtf(NS[t]), 1e-12f);
        tnn[t] = fmaxf(sqrtf(NT[t]), 1e-12f);
    }
    __syncthreads();
    float term = 0.f; int pres = 0;
    if (t < KCL) {
        const float inv = 10.f / sn[t];   // 1/TEMP = 10
        float l[KCL];
        float mx = -1e30f, diag = 0.f;
        #pragma unroll
        for (int j = 0; j < KCL; ++j) {
            l[j] = G[t * KCL + j] * inv / tnn[j];
            if (l[j] > mx) mx = l[j];
            if (j == t) diag = l[j];
        }
        float s = 0.f;
        #pragma unroll
        for (int j = 0; j < KCL; ++j) s += expf(l[j] - mx);
        float lse = logf(s) + mx;
        pres = (CNT[t] > 0) ? 1 : 0;
        term = pres ? (lse - diag) : 0.f;
    }
    #pragma unroll
    for (int off = 32; off > 0; off >>= 1) {
        term += __shfl_down(term, off);
        pres += __shfl_down(pres, off);
    }
    if (t == 0) out[0] = term / (float)pres;
}

extern "C" void kernel_launch(void* const* d_in, const int* in_sizes, int n_in,
                              void* d_out, int out_size, void* d_ws, size_t ws_size,
                              hipStream_t stream) {
    const float* fs     = (const float*)d_in[0];
    const float* ft     = (const float*)d_in[1];
    const int*   labels = (const int*)d_in[2];
    float* G  = (float*)d_ws;
    float* NS = G + KCL * KCL;
    float* NT = NS + KCL;
    int*   CNT = (int*)(NT + KCL);
    float* out = (float*)d_out;

    hipLaunchKernelGGL(init_ws, dim3(1), dim3(256), 0, stream, G);
    hipLaunchKernelGGL(main_k, dim3(BB * PP), dim3(256), 0, stream,
                       fs, ft, labels, G, NS, NT, CNT);
    hipLaunchKernelGGL(finalize, dim3(1), dim3(64), 0, stream, G, NS, NT, CNT, out);
}

// Round 6
// 322.267 us; speedup vs baseline: 1.7377x; 1.7377x over previous
//
#include <hip/hip_runtime.h>

#define KCL 41
#define BB 8
#define CC 128
#define HWSZ 25600
#define PP 200          // chunks per (b) plane = HW/C
#define TSTR 33         // tile j-stride (32 + 1 pad) -> 2-way-free banks
#define ASTR 132        // A c-stride (128 + 4 pad), float4-aligned, conflict-clean

// ---------------- init: zero accumulators in workspace ----------------
__global__ __launch_bounds__(256) void init_ws(float* ws) {
    for (int i = threadIdx.x; i < KCL * KCL + 3 * KCL; i += 256) ws[i] = 0.f;
}

// ---------------- main: per-(b,p) scatter + Gram partials ----------------
__global__ __launch_bounds__(256) void main_k(const float* __restrict__ fs,
                                              const float* __restrict__ ft,
                                              const int* __restrict__ labels,
                                              float* __restrict__ G,
                                              float* __restrict__ NS,
                                              float* __restrict__ NT,
                                              int* __restrict__ CNT)
{
    __shared__ int lab[128];
    __shared__ unsigned long long mask64[2][KCL];
    __shared__ __align__(16) float tile[2][CC][TSTR];   // 33.8 KB: both tensors, one 32-pixel j-slice
    __shared__ __align__(16) float A[2][KCL][ASTR];     // 43.3 KB: class x channel sums

    const int bp = blockIdx.x;
    const int b = bp / PP, p = bp % PP;
    const int tid = threadIdx.x;

    // zero A (absent classes must stay 0)
    {
        float* a0 = &A[0][0][0];
        for (int i = tid; i < 2 * KCL * ASTR; i += 256) a0[i] = 0.f;
    }
    if (tid < 128) lab[tid] = labels[b * HWSZ + p * 128 + tid];
    __syncthreads();

    // per-class 64-bit ballot masks over the 128 shared labels (wave-uniform)
    const int wv = tid >> 6, ln = tid & 63;
    if (wv < 2) {
        int myl = lab[(wv << 6) + ln];
        for (int cl = 0; cl < KCL; ++cl) {
            unsigned long long mm = __ballot(myl == cl);
            if (ln == 0) mask64[wv][cl] = mm;
        }
    }
    __syncthreads();
    if (tid < KCL)
        atomicAdd(&CNT[tid], (int)(__popcll(mask64[0][tid]) + __popcll(mask64[1][tid])));

    const int tn = tid >> 7;          // scatter ownership: (tensor, channel)
    const int c  = tid & 127;
    const size_t base_s = (size_t)b * CC * HWSZ + (size_t)p * 128;

    // staging: 8 float4 per thread per phase; chunk ch = tid + k*256
    //   tns = ch>>10, cs = (ch>>3)&127, j4 = ch&7  -> 8-lane-contiguous 128B global segments
    float4 ld[8];
    #pragma unroll
    for (int k = 0; k < 8; ++k) {
        int ch = tid + (k << 8);
        int tns = ch >> 10, cs = (ch >> 3) & 127, j4 = ch & 7;
        const float* f = tns ? ft : fs;
        ld[k] = *(const float4*)(f + base_s + (size_t)cs * HWSZ + (j4 << 2));
    }

    for (int s = 0; s < 4; ++s) {
        __syncthreads();   // all scatter reads of previous slice done
        // write staged registers into tile (scalar writes: stride 33 keeps banks 2-way)
        #pragma unroll
        for (int k = 0; k < 8; ++k) {
            int ch = tid + (k << 8);
            int tns = ch >> 10, cs = (ch >> 3) & 127, j4 = ch & 7;
            float* dst = &tile[tns][cs][j4 << 2];
            dst[0] = ld[k].x; dst[1] = ld[k].y; dst[2] = ld[k].z; dst[3] = ld[k].w;
        }
        // T14: issue NEXT slice's global loads now; they fly during the scatter below
        if (s < 3) {
            #pragma unroll
            for (int k = 0; k < 8; ++k) {
                int ch = tid + (k << 8);
                int tns = ch >> 10, cs = (ch >> 3) & 127, j4 = ch & 7;
                const float* f = tns ? ft : fs;
                ld[k] = *(const float4*)(f + base_s + (size_t)cs * HWSZ + ((s + 1) * 32 + (j4 << 2)));
            }
        }
        __syncthreads();
        // scatter: ALL 256 threads, one (tn,c) each; masks uniform -> no divergence
        {
            const float* trow = &tile[tn][c][0];
            const int half = s >> 1, sh = (s & 1) << 5;
            for (int cl = 0; cl < KCL; ++cl) {
                unsigned mm = (unsigned)(mask64[half][cl] >> sh);
                if (!mm) continue;                      // uniform branch
                float sum = 0.f;
                do { int j = __builtin_ctz(mm); mm &= mm - 1; sum += trow[j]; } while (mm);
                A[tn][cl][c] += sum;                    // thread-owned RMW
            }
        }
    }
    __syncthreads();

    // Gram: G[i][j] += sum_c A[0][i][c]*A[1][j][c]; 16x16 threads x 3x3 tile (48x48 >= 41x41)
    {
        const int ti = tid >> 4, tj = tid & 15;
        float acc[3][3] = {};
        for (int c4 = 0; c4 < 32; ++c4) {
            float4 av[3], bv[3];
            #pragma unroll
            for (int u = 0; u < 3; ++u) {
                int I = ti + (u << 4); if (I > KCL - 1) I = KCL - 1;
                int J = tj + (u << 4); if (J > KCL - 1) J = KCL - 1;
                av[u] = *(const float4*)(&A[0][I][c4 << 2]);
                bv[u] = *(const float4*)(&A[1][J][c4 << 2]);
            }
            #pragma unroll
            for (int u = 0; u < 3; ++u)
                #pragma unroll
                for (int v = 0; v < 3; ++v)
                    acc[u][v] += av[u].x * bv[v].x + av[u].y * bv[v].y
                               + av[u].z * bv[v].z + av[u].w * bv[v].w;
        }
        #pragma unroll
        for (int u = 0; u < 3; ++u) {
            int I = ti + (u << 4); if (I >= KCL) continue;
            #pragma unroll
            for (int v = 0; v < 3; ++v) {
                int J = tj + (v << 4); if (J >= KCL) continue;
                atomicAdd(&G[I * KCL + J], acc[u][v]);
            }
        }
    }

    // squared-norm partials
    if (tid < KCL) {
        float ss = 0.f, tt = 0.f;
        for (int c4 = 0; c4 < 32; ++c4) {
            float4 a  = *(const float4*)(&A[0][tid][c4 << 2]);
            float4 b2 = *(const float4*)(&A[1][tid][c4 << 2]);
            ss += a.x * a.x + a.y * a.y + a.z * a.z + a.w * a.w;
            tt += b2.x * b2.x + b2.y * b2.y + b2.z * b2.z + b2.w * b2.w;
        }
        atomicAdd(&NS[tid], ss);
        atomicAdd(&NT[tid], tt);
    }
}

// ---------------- finalize: cosine logits, logsumexp, loss ----------------
__global__ void finalize(const float* __restrict__ G,
                         const float* __restrict__ NS,
                         const float* __restrict__ NT,
                         const int* __restrict__ CNT,
                         float* __restrict__ out)
{
    __shared__ float sn[KCL], tnn[KCL];
    const int t = threadIdx.x;  // 64 threads = 1 wave
    if (t < KCL) {
        sn[t]  = fmaxf(sqrtf(NS[t]), 1e-12f);
        tnn[t] = fmaxf(sqrtf(NT[t]), 1e-12f);
    }
    __syncthreads();
    float term = 0.f; int pres = 0;
    if (t < KCL) {
        const float inv = 10.f / sn[t];   // 1/TEMP = 10
        float l[KCL];
        float mx = -1e30f, diag = 0.f;
        #pragma unroll
        for (int j = 0; j < KCL; ++j) {
            l[j] = G[t * KCL + j] * inv / tnn[j];
            if (l[j] > mx) mx = l[j];
            if (j == t) diag = l[j];
        }
        float s = 0.f;
        #pragma unroll
        for (int j = 0; j < KCL; ++j) s += expf(l[j] - mx);
        float lse = logf(s) + mx;
        pres = (CNT[t] > 0) ? 1 : 0;
        term = pres ? (lse - diag) : 0.f;
    }
    #pragma unroll
    for (int off = 32; off > 0; off >>= 1) {
        term += __shfl_down(term, off);
        pres += __shfl_down(pres, off);
    }
    if (t == 0) out[0] = term / (float)pres;
}

extern "C" void kernel_launch(void* const* d_in, const int* in_sizes, int n_in,
                              void* d_out, int out_size, void* d_ws, size_t ws_size,
                              hipStream_t stream) {
    const float* fs     = (const float*)d_in[0];
    const float* ft     = (const float*)d_in[1];
    const int*   labels = (const int*)d_in[2];
    float* G  = (float*)d_ws;
    float* NS = G + KCL * KCL;
    float* NT = NS + KCL;
    int*   CNT = (int*)(NT + KCL);
    float* out = (float*)d_out;

    hipLaunchKernelGGL(init_ws, dim3(1), dim3(256), 0, stream, G);
    hipLaunchKernelGGL(main_k, dim3(BB * PP), dim3(256), 0, stream,
                       fs, ft, labels, G, NS, NT, CNT);
    hipLaunchKernelGGL(finalize, dim3(1), dim3(64), 0, stream, G, NS, NT, CNT, out);
}